// Round 1
// baseline (434.791 us; speedup 1.0000x reference)
//
#include <hip/hip_runtime.h>

// LengthRegulator: B=64, T=512, D=384, MAX_LEN=4096
// Kernel A (B blocks): per-batch cumsum -> scatter idx[b,p] into d_ws (+tail -1), mel_len to out tail.
// Kernel B (B*128 blocks): pure gather/copy. Swizzled so blockIdx%8 == b%8 (batch pinned to one XCD
//   under round-robin dispatch -> x slice stays in that XCD's L2, no 8x cross-XCD re-read).
// R3: idx rows staged in LDS (one coalesced load + barrier) instead of 6 dependent
//   global idx loads per thread -> shortens the load->gather->store dependency chain.
// Output layout (flat float32): [B*ML*D] out, then [B] mel_len (as float).

#define T_DIM 512
#define D_DIM 384
#define D4    (D_DIM / 4)   // 96 float4 per row
#define ROWS  32            // output rows per copy-block
#define BLOCK 512
#define ITER  ((ROWS * D4) / BLOCK)  // 6

typedef float vfloat4 __attribute__((ext_vector_type(4)));

__global__ __launch_bounds__(BLOCK) void lr_scan_idx_kernel(
    const int* __restrict__ duration,  // [B, T]
    int*       __restrict__ idx,       // [B, ML]  (d_ws)
    float*     __restrict__ mel_out,   // [B] at out tail
    int ML)
{
    __shared__ int s_csum[T_DIM];
    const int b   = blockIdx.x;
    const int tid = threadIdx.x;

    s_csum[tid] = duration[b * T_DIM + tid];
    __syncthreads();

    // Inclusive Hillis-Steele scan (once per batch; 64 blocks total).
    for (int off = 1; off < T_DIM; off <<= 1) {
        int v = (tid >= off) ? s_csum[tid - off] : 0;
        __syncthreads();
        s_csum[tid] += v;
        __syncthreads();
    }
    const int mel = s_csum[T_DIM - 1];
    if (tid == 0) mel_out[b] = (float)mel;

    int* __restrict__ idx_b = idx + b * ML;

    // Scatter: positions [csum[t-1], csum[t]) get value t. Adjacent lanes write
    // adjacent ranges -> coalesces. (p < mel implies t <= T-1, so no clip needed.)
    const int start = (tid == 0) ? 0 : s_csum[tid - 1];
    const int end   = s_csum[tid];
    for (int p = start; p < end; ++p) idx_b[p] = tid;

    // Tail: masked positions [mel, ML) -> -1 (coalesced).
    for (int p = mel + tid; p < ML; p += BLOCK) idx_b[p] = -1;
}

__global__ __launch_bounds__(BLOCK) void lr_copy_kernel(
    const float* __restrict__ x,    // [B, T, D]
    const int*   __restrict__ idx,  // [B, ML]
    float*       __restrict__ out,  // [B, ML, D]
    int B, int ML)
{
    __shared__ int s_idx[ROWS];

    // Swizzle: b fastest so XCD = blockIdx % 8 == b % 8 (B multiple of 8).
    const int b     = blockIdx.x % B;
    const int chunk = blockIdx.x / B;
    const int row0  = chunk * ROWS;
    const int tid   = threadIdx.x;

    // One coalesced idx load for the whole block, then broadcast via LDS.
    if (tid < ROWS) s_idx[tid] = idx[b * ML + row0 + tid];
    __syncthreads();

    const vfloat4* __restrict__ x4   = (const vfloat4*)x;
    vfloat4*       __restrict__ out4 = (vfloat4*)out;

    const long long out_base = ((long long)b * ML + row0) * D4;
    const long long x_base   = (long long)b * T_DIM * D4;

    #pragma unroll
    for (int i = 0; i < ITER; ++i) {
        const int flat = tid + i * BLOCK;
        const int r = flat / D4;            // constant divisor -> magic mul
        const int j = flat - r * D4;
        const int t = s_idx[r];             // LDS broadcast, no global dep chain
        vfloat4 v = (vfloat4)(0.f, 0.f, 0.f, 0.f);
        if (t >= 0) v = x4[x_base + (long long)t * D4 + j];
        out4[out_base + flat] = v;          // plain store (nt removed: A/B vs R2)
    }
}

extern "C" void kernel_launch(void* const* d_in, const int* in_sizes, int n_in,
                              void* d_out, int out_size, void* d_ws, size_t ws_size,
                              hipStream_t stream) {
    const float* x   = (const float*)d_in[0];
    const int*   dur = (const int*)d_in[1];
    float*       out = (float*)d_out;
    int*         idx = (int*)d_ws;

    const int B  = in_sizes[1] / T_DIM;                 // 64
    const int ML = (out_size - B) / (B * D_DIM);        // 4096

    float* mel_out = out + (long long)B * ML * D_DIM;

    hipLaunchKernelGGL(lr_scan_idx_kernel, dim3(B), dim3(BLOCK), 0, stream,
                       dur, idx, mel_out, ML);

    const int grid = B * (ML / ROWS);                   // 8192 blocks
    hipLaunchKernelGGL(lr_copy_kernel, dim3(grid), dim3(BLOCK), 0, stream,
                       x, idx, out, B, ML);
}

// Round 2
// 431.487 us; speedup vs baseline: 1.0077x; 1.0077x over previous
//
#include <hip/hip_runtime.h>

// LengthRegulator: B=64, T=512, D=384, MAX_LEN=4096
// R4: single fused kernel. Each block recomputes the per-batch cumsum itself
//   (duration row = 2 KB, L2-hot across the 64 blocks of the same batch) via a
//   shfl-based scan (2 barriers, not 18), then binary-searches its 64 output
//   rows, then gather-copies. Eliminates: scan kernel dispatch + launch gap,
//   idx workspace round-trip (d_ws unused), divergent scatter + tail writes.
// Swizzle: blockIdx%8 == b%8 pins each batch's x slice to one XCD's L2.
// Output layout (flat float32): [B*ML*D] out, then [B] mel_len (as float).

#define T_DIM 512
#define D_DIM 384
#define D4    (D_DIM / 4)   // 96 float4 per row
#define ROWS  64            // output rows per block
#define BLOCK 512
#define ITER  ((ROWS * D4) / BLOCK)  // 12
#define NWAVE (BLOCK / 64)  // 8

typedef float vfloat4 __attribute__((ext_vector_type(4)));

__global__ __launch_bounds__(BLOCK) void lr_fused_kernel(
    const float* __restrict__ x,         // [B, T, D]
    const int*   __restrict__ duration,  // [B, T]
    float*       __restrict__ out,       // [B, ML, D] + [B] mel tail
    int B, int ML)
{
    __shared__ int s_csum[T_DIM];
    __shared__ int s_wsum[NWAVE];
    __shared__ int s_idx[ROWS];

    const int b     = blockIdx.x % B;   // XCD = blockIdx % 8 == b % 8
    const int chunk = blockIdx.x / B;
    const int row0  = chunk * ROWS;
    const int tid   = threadIdx.x;
    const int lane  = tid & 63;
    const int wid   = tid >> 6;

    // ---- inclusive scan of duration[b, :] (wave shfl scan + wave-sum fixup) ----
    int v = duration[b * T_DIM + tid];
    #pragma unroll
    for (int off = 1; off < 64; off <<= 1) {
        int u = __shfl_up(v, off);
        if (lane >= off) v += u;
    }
    if (lane == 63) s_wsum[wid] = v;
    __syncthreads();
    int wprefix = 0;
    #pragma unroll
    for (int w = 0; w < NWAVE - 1; ++w)
        if (w < wid) wprefix += s_wsum[w];
    s_csum[tid] = wprefix + v;
    __syncthreads();

    const int mel = s_csum[T_DIM - 1];
    if (chunk == 0 && tid == 0)
        out[(long long)B * ML * D_DIM + b] = (float)mel;

    // ---- searchsorted(csum, p, side='right') for this block's ROWS rows ----
    if (tid < ROWS) {
        const int p = row0 + tid;
        int t = -1;                      // -1 => masked (store zeros)
        if (p < mel) {
            int lo = 0, hi = T_DIM;      // first index with csum[idx] > p
            #pragma unroll
            for (int step = 0; step < 9; ++step) {
                const int mid = (lo + hi) >> 1;
                if (s_csum[mid] <= p) lo = mid + 1; else hi = mid;
            }
            t = lo;                      // p < mel implies t <= T-1 (no clip needed)
        }
        s_idx[tid] = t;
    }
    __syncthreads();

    // ---- gather copy: 64 rows x 384 floats, float4 lanes ----
    const vfloat4* __restrict__ x4   = (const vfloat4*)x;
    vfloat4*       __restrict__ out4 = (vfloat4*)out;
    const long long out_base = ((long long)b * ML + row0) * D4;
    const long long x_base   = (long long)b * T_DIM * D4;

    #pragma unroll
    for (int i = 0; i < ITER; ++i) {
        const int flat = tid + i * BLOCK;
        const int r = flat / D4;            // constant divisor -> magic mul
        const int j = flat - r * D4;
        const int t = s_idx[r];             // LDS broadcast
        vfloat4 vv = (vfloat4)(0.f, 0.f, 0.f, 0.f);
        if (t >= 0) vv = x4[x_base + (long long)t * D4 + j];
        out4[out_base + flat] = vv;         // plain store (nt was A/B'd out in R2)
    }
}

extern "C" void kernel_launch(void* const* d_in, const int* in_sizes, int n_in,
                              void* d_out, int out_size, void* d_ws, size_t ws_size,
                              hipStream_t stream) {
    const float* x   = (const float*)d_in[0];
    const int*   dur = (const int*)d_in[1];
    float*       out = (float*)d_out;
    (void)d_ws; (void)ws_size;

    const int B  = in_sizes[1] / T_DIM;                 // 64
    const int ML = (out_size - B) / (B * D_DIM);        // 4096

    const int grid = B * (ML / ROWS);                   // 4096 blocks
    hipLaunchKernelGGL(lr_fused_kernel, dim3(grid), dim3(BLOCK), 0, stream,
                       x, dur, out, B, ML);
}

// Round 3
// 419.535 us; speedup vs baseline: 1.0364x; 1.0285x over previous
//
#include <hip/hip_runtime.h>

// LengthRegulator: B=64, T=512, D=384, MAX_LEN=4096
// R5: fused kernel, scatter-built idx window (binary search REMOVED — it had an
//   off-by-one: 9 steps over [0,512] can't resolve 513 outcomes; caused absmax 5.8).
//   Each thread knows its own [start,end) in registers from the shfl scan, so it
//   scatters its token id into the block's 64-row LDS window directly: no s_csum
//   array, no dependent LDS-read chain, 2 barriers total, LDS = 288 B.
// Swizzle: blockIdx%8 == b%8 pins each batch's x slice to one XCD's L2.
// Output layout (flat float32): [B*ML*D] out, then [B] mel_len (as float).

#define T_DIM 512
#define D_DIM 384
#define D4    (D_DIM / 4)   // 96 float4 per row
#define ROWS  64            // output rows per block
#define BLOCK 512
#define ITER  ((ROWS * D4) / BLOCK)  // 12
#define NWAVE (BLOCK / 64)  // 8

typedef float vfloat4 __attribute__((ext_vector_type(4)));

__global__ __launch_bounds__(BLOCK) void lr_fused_kernel(
    const float* __restrict__ x,         // [B, T, D]
    const int*   __restrict__ duration,  // [B, T]
    float*       __restrict__ out,       // [B, ML, D] + [B] mel tail
    int B, int ML)
{
    __shared__ int s_wsum[NWAVE];
    __shared__ int s_idx[ROWS];

    const int b     = blockIdx.x % B;   // XCD = blockIdx % 8 == b % 8
    const int chunk = blockIdx.x / B;
    const int row0  = chunk * ROWS;
    const int tid   = threadIdx.x;
    const int lane  = tid & 63;
    const int wid   = tid >> 6;

    // ---- inclusive scan of duration[b,:]: wave shfl scan + wave-total fixup ----
    const int d = duration[b * T_DIM + tid];
    int v = d;
    #pragma unroll
    for (int off = 1; off < 64; off <<= 1) {
        int u = __shfl_up(v, off);
        if (lane >= off) v += u;
    }
    if (lane == 63) s_wsum[wid] = v;     // wave totals
    if (tid < ROWS) s_idx[tid] = -1;     // init window to "masked"
    __syncthreads();

    int wprefix = 0, mel = 0;
    #pragma unroll
    for (int w = 0; w < NWAVE; ++w) {
        const int s = s_wsum[w];
        if (w < wid) wprefix += s;
        mel += s;
    }
    const int end   = wprefix + v;       // inclusive csum[tid]
    const int start = end - d;           // csum[tid-1]

    // ---- scatter: token tid owns output rows [start, end); write the overlap
    //      with this block's window [row0, row0+ROWS). <=7 entries/thread. ----
    const int lo = start > row0        ? start : row0;
    const int hi = end < row0 + ROWS   ? end   : row0 + ROWS;
    for (int p = lo; p < hi; ++p) s_idx[p - row0] = tid;
    __syncthreads();

    if (chunk == 0 && tid == 0)
        out[(long long)B * ML * D_DIM + b] = (float)mel;

    // ---- gather copy: 64 rows x 384 floats, float4 lanes ----
    const vfloat4* __restrict__ x4   = (const vfloat4*)x;
    vfloat4*       __restrict__ out4 = (vfloat4*)out;
    const long long out_base = ((long long)b * ML + row0) * D4;
    const long long x_base   = (long long)b * T_DIM * D4;

    #pragma unroll
    for (int i = 0; i < ITER; ++i) {
        const int flat = tid + i * BLOCK;
        const int r = flat / D4;            // constant divisor -> magic mul
        const int j = flat - r * D4;
        const int t = s_idx[r];             // LDS broadcast
        vfloat4 vv = (vfloat4)(0.f, 0.f, 0.f, 0.f);
        if (t >= 0) vv = x4[x_base + (long long)t * D4 + j];
        out4[out_base + flat] = vv;         // plain store (nt was A/B'd out in R2)
    }
}

extern "C" void kernel_launch(void* const* d_in, const int* in_sizes, int n_in,
                              void* d_out, int out_size, void* d_ws, size_t ws_size,
                              hipStream_t stream) {
    const float* x   = (const float*)d_in[0];
    const int*   dur = (const int*)d_in[1];
    float*       out = (float*)d_out;
    (void)d_ws; (void)ws_size;

    const int B  = in_sizes[1] / T_DIM;                 // 64
    const int ML = (out_size - B) / (B * D_DIM);        // 4096

    const int grid = B * (ML / ROWS);                   // 4096 blocks
    hipLaunchKernelGGL(lr_fused_kernel, dim3(grid), dim3(BLOCK), 0, stream,
                       x, dur, out, B, ML);
}